// Round 3
// baseline (246.937 us; speedup 1.0000x reference)
//
#include <hip/hip_runtime.h>
#include <stdint.h>

// x (16,256,64,64) fp32; 32 groups; 8 heads; head dim 32. All I/O fp32.
// Intermediates bf16 in d_ws. GEMMs: bf16 MFMA 16x16x32, BK=64, swizzled
// coalesced global_load_lds staging, LDS-staged coalesced epilogue.
// Softmax folded into att: att = diag(1/l) * sum_n exp(k) v  (no max-sub; |k|<~6).
// R6: att2 as MFMA GEMM, direct global->reg frags.
// R7: attout deleted — att-output matrix folds into w_proj (W2_b = wp@blockdiag(att/l)),
//     QKV gemm writes Q transposed (qT[b][n][d]) for the final gemm.
// R8: K/V never materialized — gemm_kv_att computes K-tile and V-tile GEMMs
//     (two passes, shared staging), epilogues exp(K)/V into LDS (row-major [d][n],
//     the att-MFMA fragment layout), then per-wave-per-head att MFMAs + atomicAdd.
//     Saves 64MiB write + 64MiB read; att2 kernel deleted.
#define BATCH 16
#define CCH   256
#define NSP   4096
#define QKV_M 768

typedef unsigned short u16;
typedef short  short8 __attribute__((ext_vector_type(8)));   // 8 bf16 (4 VGPRs)
typedef float  f32x4  __attribute__((ext_vector_type(4)));

__device__ __forceinline__ float bf2f(u16 h) {
  union { unsigned int u; float f; } x; x.u = ((unsigned int)h) << 16; return x.f;
}
__device__ __forceinline__ u16 f2bf(float f) {
  union { float f; unsigned int u; } x; x.f = f;
  unsigned int r = 0x7fffu + ((x.u >> 16) & 1u);
  return (u16)((x.u + r) >> 16);
}

#define GLB(p) ((__attribute__((address_space(1))) void*)(p))
#define LDSP(p) ((__attribute__((address_space(3))) void*)(p))

// ------------------------------------------------ weights fp32 -> bf16
__global__ __launch_bounds__(256) void convw_kernel(const float* __restrict__ wq,
                                                    const float* __restrict__ wp,
                                                    u16* __restrict__ dst) {
  const int i = (blockIdx.x * 256 + threadIdx.x) * 4;
  float4 v = (i < 196608) ? *(const float4*)(wq + i)
                          : *(const float4*)(wp + (i - 196608));
  ushort4 o;
  o.x = f2bf(v.x); o.y = f2bf(v.y); o.z = f2bf(v.z); o.w = f2bf(v.w);
  *(ushort4*)(dst + i) = o;
}

// ------------------------------------------------ GroupNorm stats (+ zero att accum)
__global__ __launch_bounds__(256) void gn_stats(const float* __restrict__ x,
                                                float2* __restrict__ stats,
                                                float* __restrict__ att4) {
  const int blk = blockIdx.x;
  const int tid = threadIdx.x;
  // zero att accumulator: 128 heads * 1056 floats = 512 blocks * 264
  {
    float* az = att4 + (size_t)blk * 264;
    for (int i = tid; i < 264; i += 256) az[i] = 0.f;
  }
  const float4* xv = (const float4*)(x + (size_t)blk * 32768);
  float s = 0.f, ss = 0.f;
  for (int i = tid; i < 8192; i += 256) {
    float4 u = xv[i];
    s  += u.x + u.y + u.z + u.w;
    ss += u.x * u.x + u.y * u.y + u.z * u.z + u.w * u.w;
  }
#pragma unroll
  for (int off = 32; off > 0; off >>= 1) {
    s  += __shfl_down(s, off);
    ss += __shfl_down(ss, off);
  }
  __shared__ float red[8];
  const int wave = tid >> 6, lane = tid & 63;
  if (lane == 0) { red[wave * 2] = s; red[wave * 2 + 1] = ss; }
  __syncthreads();
  if (tid == 0) {
    const float S  = red[0] + red[2] + red[4] + red[6];
    const float SS = red[1] + red[3] + red[5] + red[7];
    const float mean = S * (1.f / 32768.f);
    const float var  = SS * (1.f / 32768.f) - mean * mean;
    stats[blk] = make_float2(mean, rsqrtf(var + 1e-5f));
  }
}

// ------------------------------------------------ GN apply + transpose
__global__ __launch_bounds__(256) void gn_apply_t(const float* __restrict__ x,
                                                  const float* __restrict__ gw,
                                                  const float* __restrict__ gb,
                                                  const float2* __restrict__ stats,
                                                  u16* __restrict__ xnT) {
  __shared__ u16 ls[64][72];                    // [c][n], pad 72
  const int b = blockIdx.z, c0 = blockIdx.y * 64, n0 = blockIdx.x * 64;
  const int tid = threadIdx.x;
#pragma unroll
  for (int r = 0; r < 4; ++r) {
    const int cc = (tid >> 4) + r * 16;
    const int nn = (tid & 15) * 4;
    const int c = c0 + cc;
    const float2 st = stats[b * 32 + (c >> 3)];
    const float wv = gw[c] * st.y;
    const float bv = gb[c] - st.x * wv;
    float4 u = *(const float4*)(x + ((size_t)b * CCH + c) * NSP + n0 + nn);
    ushort4 o;
    o.x = f2bf(u.x * wv + bv);
    o.y = f2bf(u.y * wv + bv);
    o.z = f2bf(u.z * wv + bv);
    o.w = f2bf(u.w * wv + bv);
    *(ushort4*)&ls[cc][nn] = o;
  }
  __syncthreads();
#pragma unroll
  for (int p = 0; p < 2; ++p) {
    const int idx = tid + p * 256;              // 0..511
    const int nn = idx >> 3;
    const int cb = (idx & 7) * 8;
    u16 tmp[8];
#pragma unroll
    for (int j = 0; j < 8; ++j) tmp[j] = ls[cb + j][nn];
    *(uint4*)(xnT + ((size_t)b * NSP + n0 + nn) * CCH + c0 + cb) = *(uint4*)tmp;
  }
}

// ------------------------------------------------ MFMA GEMM, BK=64, coalesced staging
// C[b][m][n] = sum_c A[m][c]*Bt[b][n][c]; A bf16 MxK(K=256), Bt bf16 NxK.
// OUTF32: fp32 output + bias. TRQ: rows m0<256 are written TRANSPOSED as
// qT[b][n][m] into the same C buffer (Q part of qkv), K/V rows unchanged.
template <int OUTF32, int TRQ>
__global__ __launch_bounds__(256) void gemm_mfma(const u16* __restrict__ A,
                                                 const u16* __restrict__ Bt,
                                                 const float* __restrict__ bias,
                                                 void* __restrict__ Cm, int M,
                                                 int aBatch, long btStride) {
  __shared__ __align__(16) u16 smem[17408];     // 34816 B: staging 32KB / C-tile epi
  const int tid = threadIdx.x, wave = tid >> 6, lane = tid & 63;
  const int n0 = blockIdx.x * 128, m0 = blockIdx.y * 128, bz = blockIdx.z;
  const u16* Ab = A + (size_t)bz * aBatch;
  const u16* Bb = Bt + (size_t)bz * btStride;

  const int lrow = lane >> 3;                   // 0..7: row within 8-row group
  const int kcl  = ((lane & 7) ^ lrow) * 8;     // swizzled k element offset
  const u16* pA[4]; const u16* pB[4];
#pragma unroll
  for (int j = 0; j < 4; ++j) {
    const int row = j * 32 + wave * 8 + lrow;
    pA[j] = Ab + (size_t)(m0 + row) * CCH + kcl;
    pB[j] = Bb + (size_t)(n0 + row) * CCH + kcl;
  }
  u16* lA = smem;                               // 1024 granules (16KB)
  u16* lB = smem + 8192;                        // 1024 granules (16KB)

  const int wm = wave >> 1, wn = wave & 1;
  f32x4 acc[4][4];
#pragma unroll
  for (int i = 0; i < 4; ++i)
#pragma unroll
    for (int j = 0; j < 4; ++j) acc[i][j] = (f32x4){0.f, 0.f, 0.f, 0.f};

  for (int it = 0; it < 4; ++it) {              // K = 256, BK = 64
#pragma unroll
    for (int j = 0; j < 4; ++j) {
      __builtin_amdgcn_global_load_lds(GLB(pA[j]), LDSP(lA + (j * 256 + wave * 64) * 8), 16, 0, 0);
      __builtin_amdgcn_global_load_lds(GLB(pB[j]), LDSP(lB + (j * 256 + wave * 64) * 8), 16, 0, 0);
      pA[j] += 64; pB[j] += 64;
    }
    __syncthreads();
#pragma unroll
    for (int w = 0; w < 2; ++w) {               // two 32-k windows
      const int kcf = w * 4 + (lane >> 4);
      short8 af[4], bfr[4];
#pragma unroll
      for (int mt = 0; mt < 4; ++mt) {
        const int row = wm * 64 + mt * 16 + (lane & 15);
        af[mt] = *(const short8*)&lA[(row * 8 + (kcf ^ (row & 7))) * 8];
      }
#pragma unroll
      for (int nt = 0; nt < 4; ++nt) {
        const int row = wn * 64 + nt * 16 + (lane & 15);
        bfr[nt] = *(const short8*)&lB[(row * 8 + (kcf ^ (row & 7))) * 8];
      }
#pragma unroll
      for (int mt = 0; mt < 4; ++mt)
#pragma unroll
        for (int nt = 0; nt < 4; ++nt)
          acc[mt][nt] = __builtin_amdgcn_mfma_f32_16x16x32_bf16(af[mt], bfr[nt], acc[mt][nt], 0, 0, 0);
    }
    __syncthreads();
  }

  // epilogue: C/D frag col=lane&15, row=(lane>>4)*4+reg
  if (!OUTF32) {
    u16* cl = smem;                             // [128][136] u16 (34816 B)
    const bool tr = TRQ && (m0 < 256);          // uniform per block
#pragma unroll
    for (int mt = 0; mt < 4; ++mt)
#pragma unroll
      for (int nt = 0; nt < 4; ++nt)
#pragma unroll
        for (int r = 0; r < 4; ++r) {
          const int row = wm * 64 + mt * 16 + (lane >> 4) * 4 + r;
          const int col = wn * 64 + nt * 16 + (lane & 15);
          if (tr) cl[col * 136 + row] = f2bf(acc[mt][nt][r]);   // tile stored n-major
          else    cl[row * 136 + col] = f2bf(acc[mt][nt][r]);
        }
    __syncthreads();
    u16* C = (u16*)Cm + (size_t)bz * M * NSP;
    if (tr) {
      // cl is [n_local][m]; write qT[b][n][m] rows: full 256B m-contig chunks
#pragma unroll
      for (int j = 0; j < 8; ++j) {
        const int idx = tid + j * 256;          // 0..2047
        const int nl = idx >> 4, mc = (idx & 15) * 8;
        *(uint4*)(C + (size_t)(n0 + nl) * CCH + m0 + mc) =
            *(const uint4*)&cl[nl * 136 + mc];
      }
    } else {
#pragma unroll
      for (int j = 0; j < 8; ++j) {
        const int idx = tid + j * 256;          // 0..2047
        const int row = idx >> 4, chunk = idx & 15;
        *(uint4*)(C + (size_t)(m0 + row) * NSP + n0 + chunk * 8) =
            *(const uint4*)&cl[row * 136 + chunk * 8];
      }
    }
  } else {
    float* clf = (float*)smem;                  // [64][132] fp32 per pass (33792 B)
    float* C = (float*)Cm + (size_t)bz * M * NSP;
#pragma unroll
    for (int pass = 0; pass < 2; ++pass) {
      if (wm == pass) {
#pragma unroll
        for (int mt = 0; mt < 4; ++mt)
#pragma unroll
          for (int nt = 0; nt < 4; ++nt)
#pragma unroll
            for (int r = 0; r < 4; ++r) {
              const int rl = mt * 16 + (lane >> 4) * 4 + r;   // 0..63
              const int col = wn * 64 + nt * 16 + (lane & 15);
              clf[rl * 132 + col] = acc[mt][nt][r] + bias[m0 + pass * 64 + rl];
            }
      }
      __syncthreads();
#pragma unroll
      for (int j = 0; j < 8; ++j) {
        const int idx = tid + j * 256;          // 0..2047
        const int row = idx >> 5, chunk = idx & 31;
        *(float4*)(C + (size_t)(m0 + pass * 64 + row) * NSP + n0 + chunk * 4) =
            *(const float4*)&clf[row * 132 + chunk * 4];
      }
      __syncthreads();
    }
  }
}

// ------------------------------------------------ fused K/V GEMM + att reduction
// Block: n-chunk of 128, head-group hg (4 heads = 128 K-rows + 128 V-rows), batch b.
// Pass 0: K-tile GEMM -> exp -> bf16 -> clK (LDS, [128][136]).
// Pass 1: V-tile GEMM -> bf16 -> clV (LDS, overlaps staging region).
// Then wave w = head hg*4+w: att[32][32] += ek @ v^T, l += ek @ ones via MFMA,
// atomicAdd into att4. K/V never written to global.
__global__ __launch_bounds__(256) void gemm_kv_att(const u16* __restrict__ A,
                                                   const u16* __restrict__ Bt,
                                                   float* __restrict__ att4) {
  __shared__ __align__(16) u16 smem[34816];     // 69632 B: [0,17408)=staging/clV, [17408,34816)=clK
  const int tid = threadIdx.x, wave = tid >> 6, lane = tid & 63;
  const int n0 = blockIdx.x * 128, hg = blockIdx.y, b = blockIdx.z;
  const u16* Bb = Bt + (size_t)b * (size_t)NSP * CCH;

  const int lrow = lane >> 3;                   // 0..7
  const int kcl  = ((lane & 7) ^ lrow) * 8;     // swizzled k element offset
  u16* lA  = smem;                              // 16 KB
  u16* lB  = smem + 8192;                       // 16 KB
  u16* clK = smem + 17408;                      // [128][136] u16
  u16* clV = smem;                              // [128][136] u16 (after staging done)
  const int wm = wave >> 1, wn = wave & 1;

  for (int pass = 0; pass < 2; ++pass) {
    const int m0 = 256 + pass * 256 + hg * 128; // K rows then V rows
    const u16* pA[4]; const u16* pB[4];
#pragma unroll
    for (int j = 0; j < 4; ++j) {
      const int row = j * 32 + wave * 8 + lrow;
      pA[j] = A  + (size_t)(m0 + row) * CCH + kcl;
      pB[j] = Bb + (size_t)(n0 + row) * CCH + kcl;
    }
    f32x4 acc[4][4];
#pragma unroll
    for (int i = 0; i < 4; ++i)
#pragma unroll
      for (int j = 0; j < 4; ++j) acc[i][j] = (f32x4){0.f, 0.f, 0.f, 0.f};

    for (int it = 0; it < 4; ++it) {            // K = 256, BK = 64
#pragma unroll
      for (int j = 0; j < 4; ++j) {
        __builtin_amdgcn_global_load_lds(GLB(pA[j]), LDSP(lA + (j * 256 + wave * 64) * 8), 16, 0, 0);
        __builtin_amdgcn_global_load_lds(GLB(pB[j]), LDSP(lB + (j * 256 + wave * 64) * 8), 16, 0, 0);
        pA[j] += 64; pB[j] += 64;
      }
      __syncthreads();
#pragma unroll
      for (int w = 0; w < 2; ++w) {
        const int kcf = w * 4 + (lane >> 4);
        short8 af[4], bfr[4];
#pragma unroll
        for (int mt = 0; mt < 4; ++mt) {
          const int row = wm * 64 + mt * 16 + (lane & 15);
          af[mt] = *(const short8*)&lA[(row * 8 + (kcf ^ (row & 7))) * 8];
        }
#pragma unroll
        for (int nt = 0; nt < 4; ++nt) {
          const int row = wn * 64 + nt * 16 + (lane & 15);
          bfr[nt] = *(const short8*)&lB[(row * 8 + (kcf ^ (row & 7))) * 8];
        }
#pragma unroll
        for (int mt = 0; mt < 4; ++mt)
#pragma unroll
          for (int nt = 0; nt < 4; ++nt)
            acc[mt][nt] = __builtin_amdgcn_mfma_f32_16x16x32_bf16(af[mt], bfr[nt], acc[mt][nt], 0, 0, 0);
      }
      __syncthreads();
    }

    // epilogue -> LDS tile [128][136], row = m-local (d), col = n-local
    u16* cl = pass ? clV : clK;                 // clK safe during pass1 (region1)
#pragma unroll
    for (int mt = 0; mt < 4; ++mt)
#pragma unroll
      for (int nt = 0; nt < 4; ++nt)
#pragma unroll
        for (int r = 0; r < 4; ++r) {
          const int row = wm * 64 + mt * 16 + (lane >> 4) * 4 + r;
          const int col = wn * 64 + nt * 16 + (lane & 15);
          const float v = acc[mt][nt][r];
          cl[row * 136 + col] = f2bf(pass ? v : __expf(v));
        }
  }
  __syncthreads();                              // clK + clV visible to all waves

  // att phase: wave = head within group
  const int hh = wave;
  const int bh = b * 8 + hg * 4 + hh;
  f32x4 a2[2][2], al[2];
#pragma unroll
  for (int i = 0; i < 2; ++i) {
    al[i] = (f32x4){0.f, 0.f, 0.f, 0.f};
#pragma unroll
    for (int j = 0; j < 2; ++j) a2[i][j] = (f32x4){0.f, 0.f, 0.f, 0.f};
  }
  short8 ones;
#pragma unroll
  for (int j = 0; j < 8; ++j) ones[j] = (short)0x3F80;   // bf16 1.0

  const int rr = lane & 15, cc8 = (lane >> 4) * 8;
#pragma unroll
  for (int c = 0; c < 4; ++c) {                 // 4 chunks of 32 n
    const int n = c * 32 + cc8;
    short8 ek0 = *(const short8*)&clK[(hh * 32 + rr) * 136 + n];
    short8 ek1 = *(const short8*)&clK[(hh * 32 + 16 + rr) * 136 + n];
    short8 v0  = *(const short8*)&clV[(hh * 32 + rr) * 136 + n];
    short8 v1  = *(const short8*)&clV[(hh * 32 + 16 + rr) * 136 + n];
    a2[0][0] = __builtin_amdgcn_mfma_f32_16x16x32_bf16(ek0, v0, a2[0][0], 0, 0, 0);
    a2[0][1] = __builtin_amdgcn_mfma_f32_16x16x32_bf16(ek0, v1, a2[0][1], 0, 0, 0);
    a2[1][0] = __builtin_amdgcn_mfma_f32_16x16x32_bf16(ek1, v0, a2[1][0], 0, 0, 0);
    a2[1][1] = __builtin_amdgcn_mfma_f32_16x16x32_bf16(ek1, v1, a2[1][1], 0, 0, 0);
    al[0]    = __builtin_amdgcn_mfma_f32_16x16x32_bf16(ek0, ones, al[0], 0, 0, 0);
    al[1]    = __builtin_amdgcn_mfma_f32_16x16x32_bf16(ek1, ones, al[1], 0, 0, 0);
  }

  // C frag: col(lane&15)=e, row=(lane>>4)*4+j=d
  float* ap = att4 + (size_t)bh * 1056;
  const int dq = (lane >> 4) * 4;
#pragma unroll
  for (int dh = 0; dh < 2; ++dh) {
#pragma unroll
    for (int eh = 0; eh < 2; ++eh)
#pragma unroll
      for (int j = 0; j < 4; ++j)
        atomicAdd(&ap[(dh * 16 + dq + j) * 32 + eh * 16 + rr], a2[dh][eh][j]);
    if (rr == 0)
#pragma unroll
      for (int j = 0; j < 4; ++j)
        atomicAdd(&ap[1024 + dh * 16 + dq + j], al[dh][j]);
  }
}

// ------------------------------------------------ W2_b = wp @ blockdiag(att/l)
// W2[b][o][h*32+d] = sum_e wp[o][h*32+e] * att[bh][d][e]/l[bh][d].
// grid 256 = 16 b x 16 o-tiles; thread = output column c' = h*32+d.
__global__ __launch_bounds__(256) void w2_kernel(const u16* __restrict__ wp_bf,
                                                 const float* __restrict__ att4,
                                                 u16* __restrict__ W2) {
  const int b = blockIdx.x >> 4;
  const int o0 = (blockIdx.x & 15) * 16;
  const int tid = threadIdx.x;
  const int h = tid >> 5, d = tid & 31;
  const float* ap = att4 + ((size_t)b * 8 + h) * 1056;
  const float linv = 1.f / ap[1024 + d];
  float as[32];
#pragma unroll
  for (int e = 0; e < 32; ++e) as[e] = ap[d * 32 + e] * linv;
  u16* w2p = W2 + (size_t)b * 65536;
  for (int oi = 0; oi < 16; ++oi) {
    const int o = o0 + oi;
    const uint4* wr = (const uint4*)(wp_bf + o * 256 + h * 32);
    float acc = 0.f;
#pragma unroll
    for (int j = 0; j < 4; ++j) {
      uint4 u = wr[j];
      const u16* w8 = (const u16*)&u;
#pragma unroll
      for (int t = 0; t < 8; ++t) acc += bf2f(w8[t]) * as[j * 8 + t];
    }
    w2p[o * 256 + tid] = f2bf(acc);             // coalesced u16 row writes
  }
}

// ------------------------------------------------ launch
extern "C" void kernel_launch(void* const* d_in, const int* in_sizes, int n_in,
                              void* d_out, int out_size, void* d_ws, size_t ws_size,
                              hipStream_t stream) {
  const float* x      = (const float*)d_in[0];
  const float* gn_w   = (const float*)d_in[1];
  const float* gn_b   = (const float*)d_in[2];
  const float* w_qkv  = (const float*)d_in[3];
  const float* w_proj = (const float*)d_in[4];
  const float* b_proj = (const float*)d_in[5];
  float* out = (float*)d_out;

  char* ws = (char*)d_ws;
  u16*    xnT   = (u16*)ws;                                 // 32 MiB [b][n][c]; reused as W2 after QKV gemm
  u16*    qkv   = (u16*)(ws + 33554432ull);                 // Q region only: qT[b][n][256]
  float*  att4  = (float*)(ws + 134217728ull);              // 128*1056*4 = 540672 B
  float2* stats = (float2*)(ws + 134758400ull);             // 4 KiB
  u16*    wbf   = (u16*)(ws + 134762496ull);                // 512 KiB
  u16* wq_bf = wbf;
  u16* wp_bf = wbf + 196608;
  u16* W2 = xnT;                                            // 2 MiB, xnT free after gemms

  convw_kernel<<<256, 256, 0, stream>>>(w_qkv, w_proj, wbf);
  gn_stats<<<512, 256, 0, stream>>>(x, stats, att4);
  gn_apply_t<<<dim3(64, 4, 16), 256, 0, stream>>>(x, gn_w, gn_b, stats, xnT);
  gemm_mfma<0, 1><<<dim3(32, 2, 16), 256, 0, stream>>>(wq_bf, xnT, nullptr, qkv,
                                                       QKV_M, 0, (long)NSP * CCH);
  gemm_kv_att<<<dim3(32, 2, 16), 256, 0, stream>>>(wq_bf, xnT, att4);
  w2_kernel<<<256, 256, 0, stream>>>(wp_bf, att4, W2);
  gemm_mfma<1, 0><<<dim3(32, 2, 16), 256, 0, stream>>>(W2, qkv, b_proj, out,
                                                       CCH, 65536, (long)QKV_M * NSP);
}

// Round 4
// 223.546 us; speedup vs baseline: 1.1046x; 1.1046x over previous
//
#include <hip/hip_runtime.h>
#include <stdint.h>

// x (16,256,64,64) fp32; 32 groups; 8 heads; head dim 32. All I/O fp32.
// Intermediates bf16 in d_ws. GEMMs: bf16 MFMA 16x16x32, BK=64, swizzled
// coalesced global_load_lds staging, LDS-staged coalesced epilogue.
// Softmax folded into att: att = diag(1/l) * sum_n exp(k) v  (no max-sub; |k|<~6).
// R7: att-output matrix folds into w_proj: W2_b = wp @ blockdiag(att/l).
// R8: K/V never materialized — gemm_kv_att computes K/V tiles, epilogues into
//     LDS ([d][n] = att-MFMA fragment layout), per-head att MFMAs + atomicAdd.
// R9: (a) kv_att re-tiled 64mx128n (2 heads/block): LDS 41984B -> 3 blocks/CU
//         (was 69632B -> 2), grid 2048; per-block LDS reduce before atomics.
//     (b) Q never materialized either: out = (W2_b @ Wq_q) @ xn. W3 = W2@Wq_q
//         per-batch 256^3 (tiny gemm + one 256x256 transpose of Wq_q);
//         Q-gemm (8.6 GF + 64MiB round trip) deleted; final gemm reads xnT.
#define BATCH 16
#define CCH   256
#define NSP   4096

typedef unsigned short u16;
typedef short  short8 __attribute__((ext_vector_type(8)));   // 8 bf16 (4 VGPRs)
typedef float  f32x4  __attribute__((ext_vector_type(4)));

__device__ __forceinline__ float bf2f(u16 h) {
  union { unsigned int u; float f; } x; x.u = ((unsigned int)h) << 16; return x.f;
}
__device__ __forceinline__ u16 f2bf(float f) {
  union { float f; unsigned int u; } x; x.f = f;
  unsigned int r = 0x7fffu + ((x.u >> 16) & 1u);
  return (u16)((x.u + r) >> 16);
}

#define GLB(p) ((__attribute__((address_space(1))) void*)(p))
#define LDSP(p) ((__attribute__((address_space(3))) void*)(p))

// ------------------------------------------------ weights fp32 -> bf16
__global__ __launch_bounds__(256) void convw_kernel(const float* __restrict__ wq,
                                                    const float* __restrict__ wp,
                                                    u16* __restrict__ dst) {
  const int i = (blockIdx.x * 256 + threadIdx.x) * 4;
  float4 v = (i < 196608) ? *(const float4*)(wq + i)
                          : *(const float4*)(wp + (i - 196608));
  ushort4 o;
  o.x = f2bf(v.x); o.y = f2bf(v.y); o.z = f2bf(v.z); o.w = f2bf(v.w);
  *(ushort4*)(dst + i) = o;
}

// ------------------------------------------------ wqT[c][d] = wq_bf[d][c] (Q rows)
__global__ __launch_bounds__(256) void wqt_kernel(const u16* __restrict__ wq_bf,
                                                  u16* __restrict__ wqT) {
  __shared__ u16 ls[64][72];
  const int r0 = blockIdx.y * 64, c0 = blockIdx.x * 64;
  const int t = threadIdx.x;
#pragma unroll
  for (int j = 0; j < 2; ++j) {
    const int row = j * 32 + (t >> 3), col8 = (t & 7) * 8;
    *(uint4*)&ls[row][col8] = *(const uint4*)(wq_bf + (r0 + row) * 256 + c0 + col8);
  }
  __syncthreads();
#pragma unroll
  for (int j = 0; j < 2; ++j) {
    const int crow = j * 32 + (t >> 3), d8 = (t & 7) * 8;
    u16 tmp[8];
#pragma unroll
    for (int k = 0; k < 8; ++k) tmp[k] = ls[d8 + k][crow];
    *(uint4*)(wqT + (c0 + crow) * 256 + r0 + d8) = *(uint4*)tmp;
  }
}

// ------------------------------------------------ GroupNorm stats (+ zero att accum)
__global__ __launch_bounds__(256) void gn_stats(const float* __restrict__ x,
                                                float2* __restrict__ stats,
                                                float* __restrict__ att4) {
  const int blk = blockIdx.x;
  const int tid = threadIdx.x;
  {
    float* az = att4 + (size_t)blk * 264;
    for (int i = tid; i < 264; i += 256) az[i] = 0.f;
  }
  const float4* xv = (const float4*)(x + (size_t)blk * 32768);
  float s = 0.f, ss = 0.f;
  for (int i = tid; i < 8192; i += 256) {
    float4 u = xv[i];
    s  += u.x + u.y + u.z + u.w;
    ss += u.x * u.x + u.y * u.y + u.z * u.z + u.w * u.w;
  }
#pragma unroll
  for (int off = 32; off > 0; off >>= 1) {
    s  += __shfl_down(s, off);
    ss += __shfl_down(ss, off);
  }
  __shared__ float red[8];
  const int wave = tid >> 6, lane = tid & 63;
  if (lane == 0) { red[wave * 2] = s; red[wave * 2 + 1] = ss; }
  __syncthreads();
  if (tid == 0) {
    const float S  = red[0] + red[2] + red[4] + red[6];
    const float SS = red[1] + red[3] + red[5] + red[7];
    const float mean = S * (1.f / 32768.f);
    const float var  = SS * (1.f / 32768.f) - mean * mean;
    stats[blk] = make_float2(mean, rsqrtf(var + 1e-5f));
  }
}

// ------------------------------------------------ GN apply + transpose
__global__ __launch_bounds__(256) void gn_apply_t(const float* __restrict__ x,
                                                  const float* __restrict__ gw,
                                                  const float* __restrict__ gb,
                                                  const float2* __restrict__ stats,
                                                  u16* __restrict__ xnT) {
  __shared__ u16 ls[64][72];                    // [c][n], pad 72
  const int b = blockIdx.z, c0 = blockIdx.y * 64, n0 = blockIdx.x * 64;
  const int tid = threadIdx.x;
#pragma unroll
  for (int r = 0; r < 4; ++r) {
    const int cc = (tid >> 4) + r * 16;
    const int nn = (tid & 15) * 4;
    const int c = c0 + cc;
    const float2 st = stats[b * 32 + (c >> 3)];
    const float wv = gw[c] * st.y;
    const float bv = gb[c] - st.x * wv;
    float4 u = *(const float4*)(x + ((size_t)b * CCH + c) * NSP + n0 + nn);
    ushort4 o;
    o.x = f2bf(u.x * wv + bv);
    o.y = f2bf(u.y * wv + bv);
    o.z = f2bf(u.z * wv + bv);
    o.w = f2bf(u.w * wv + bv);
    *(ushort4*)&ls[cc][nn] = o;
  }
  __syncthreads();
#pragma unroll
  for (int p = 0; p < 2; ++p) {
    const int idx = tid + p * 256;              // 0..511
    const int nn = idx >> 3;
    const int cb = (idx & 7) * 8;
    u16 tmp[8];
#pragma unroll
    for (int j = 0; j < 8; ++j) tmp[j] = ls[cb + j][nn];
    *(uint4*)(xnT + ((size_t)b * NSP + n0 + nn) * CCH + c0 + cb) = *(uint4*)tmp;
  }
}

// ------------------------------------------------ MFMA GEMM, BK=64, coalesced staging
// C[b][m][n] = sum_c A[m][c]*Bt[b][n][c]; A bf16 MxK(K=256), Bt bf16 NxK.
// OUTF32: fp32 output + bias. ldc = output row stride.
template <int OUTF32>
__global__ __launch_bounds__(256) void gemm_mfma(const u16* __restrict__ A,
                                                 const u16* __restrict__ Bt,
                                                 const float* __restrict__ bias,
                                                 void* __restrict__ Cm, int M,
                                                 int aBatch, long btStride, int ldc) {
  __shared__ __align__(16) u16 smem[17408];     // 34816 B: staging 32KB / C-tile epi
  const int tid = threadIdx.x, wave = tid >> 6, lane = tid & 63;
  const int n0 = blockIdx.x * 128, m0 = blockIdx.y * 128, bz = blockIdx.z;
  const u16* Ab = A + (size_t)bz * aBatch;
  const u16* Bb = Bt + (size_t)bz * btStride;

  const int lrow = lane >> 3;                   // 0..7: row within 8-row group
  const int kcl  = ((lane & 7) ^ lrow) * 8;     // swizzled k element offset
  const u16* pA[4]; const u16* pB[4];
#pragma unroll
  for (int j = 0; j < 4; ++j) {
    const int row = j * 32 + wave * 8 + lrow;
    pA[j] = Ab + (size_t)(m0 + row) * CCH + kcl;
    pB[j] = Bb + (size_t)(n0 + row) * CCH + kcl;
  }
  u16* lA = smem;                               // 1024 granules (16KB)
  u16* lB = smem + 8192;                        // 1024 granules (16KB)

  const int wm = wave >> 1, wn = wave & 1;
  f32x4 acc[4][4];
#pragma unroll
  for (int i = 0; i < 4; ++i)
#pragma unroll
    for (int j = 0; j < 4; ++j) acc[i][j] = (f32x4){0.f, 0.f, 0.f, 0.f};

  for (int it = 0; it < 4; ++it) {              // K = 256, BK = 64
#pragma unroll
    for (int j = 0; j < 4; ++j) {
      __builtin_amdgcn_global_load_lds(GLB(pA[j]), LDSP(lA + (j * 256 + wave * 64) * 8), 16, 0, 0);
      __builtin_amdgcn_global_load_lds(GLB(pB[j]), LDSP(lB + (j * 256 + wave * 64) * 8), 16, 0, 0);
      pA[j] += 64; pB[j] += 64;
    }
    __syncthreads();
#pragma unroll
    for (int w = 0; w < 2; ++w) {               // two 32-k windows
      const int kcf = w * 4 + (lane >> 4);
      short8 af[4], bfr[4];
#pragma unroll
      for (int mt = 0; mt < 4; ++mt) {
        const int row = wm * 64 + mt * 16 + (lane & 15);
        af[mt] = *(const short8*)&lA[(row * 8 + (kcf ^ (row & 7))) * 8];
      }
#pragma unroll
      for (int nt = 0; nt < 4; ++nt) {
        const int row = wn * 64 + nt * 16 + (lane & 15);
        bfr[nt] = *(const short8*)&lB[(row * 8 + (kcf ^ (row & 7))) * 8];
      }
#pragma unroll
      for (int mt = 0; mt < 4; ++mt)
#pragma unroll
        for (int nt = 0; nt < 4; ++nt)
          acc[mt][nt] = __builtin_amdgcn_mfma_f32_16x16x32_bf16(af[mt], bfr[nt], acc[mt][nt], 0, 0, 0);
    }
    __syncthreads();
  }

  // epilogue: C/D frag col=lane&15, row=(lane>>4)*4+reg
  if (!OUTF32) {
    u16* cl = smem;                             // [128][136] u16 (34816 B)
#pragma unroll
    for (int mt = 0; mt < 4; ++mt)
#pragma unroll
      for (int nt = 0; nt < 4; ++nt)
#pragma unroll
        for (int r = 0; r < 4; ++r) {
          const int row = wm * 64 + mt * 16 + (lane >> 4) * 4 + r;
          const int col = wn * 64 + nt * 16 + (lane & 15);
          cl[row * 136 + col] = f2bf(acc[mt][nt][r]);
        }
    __syncthreads();
    u16* C = (u16*)Cm + (size_t)bz * (size_t)M * ldc;
#pragma unroll
    for (int j = 0; j < 8; ++j) {
      const int idx = tid + j * 256;            // 0..2047
      const int row = idx >> 4, chunk = idx & 15;
      *(uint4*)(C + (size_t)(m0 + row) * ldc + n0 + chunk * 8) =
          *(const uint4*)&cl[row * 136 + chunk * 8];
    }
  } else {
    float* clf = (float*)smem;                  // [64][132] fp32 per pass (33792 B)
    float* C = (float*)Cm + (size_t)bz * (size_t)M * ldc;
#pragma unroll
    for (int pass = 0; pass < 2; ++pass) {
      if (wm == pass) {
#pragma unroll
        for (int mt = 0; mt < 4; ++mt)
#pragma unroll
          for (int nt = 0; nt < 4; ++nt)
#pragma unroll
            for (int r = 0; r < 4; ++r) {
              const int rl = mt * 16 + (lane >> 4) * 4 + r;   // 0..63
              const int col = wn * 64 + nt * 16 + (lane & 15);
              clf[rl * 132 + col] = acc[mt][nt][r] + bias[m0 + pass * 64 + rl];
            }
      }
      __syncthreads();
#pragma unroll
      for (int j = 0; j < 8; ++j) {
        const int idx = tid + j * 256;          // 0..2047
        const int row = idx >> 5, chunk = idx & 31;
        *(float4*)(C + (size_t)(m0 + pass * 64 + row) * ldc + n0 + chunk * 4) =
            *(const float4*)&clf[row * 132 + chunk * 4];
      }
      __syncthreads();
    }
  }
}

// ------------------------------------------------ fused K/V GEMM + att reduction
// Block: 128-n chunk, head pair hg (64 K-rows + 64 V-rows), batch b.
// Pass 0: K-tile 64x128 GEMM -> exp -> bf16 -> clK. Pass 1: V -> clV (staging region).
// att: wave (hh=wave>>1, nhalf=wave&1): 6 MFMAs x 2 chunks on head hh's LDS rows;
// nhalf pair reduced in LDS, then atomicAdd into att4.
// LDS 41984 B -> 3 blocks/CU (R3 post-mortem: 69632 B -> 2 blocks -> 10% occ).
__global__ __launch_bounds__(256) void gemm_kv_att(const u16* __restrict__ A,
                                                   const u16* __restrict__ Bt,
                                                   float* __restrict__ att4) {
  __shared__ __align__(16) u16 smem[20992];     // 41984 B
  const int tid = threadIdx.x, wave = tid >> 6, lane = tid & 63;
  const int n0 = blockIdx.x * 128, hg = blockIdx.y, b = blockIdx.z;
  const u16* Bb = Bt + (size_t)b * (size_t)NSP * CCH;

  const int lrow = lane >> 3;                   // 0..7
  const int kcl  = ((lane & 7) ^ lrow) * 8;     // swizzled k element offset
  u16* lA  = smem;                              // 8 KB (512 granules)
  u16* lB  = smem + 4096;                       // 16 KB (1024 granules)
  u16* clV = smem;                              // [64][136] u16, reuses staging region
  u16* clK = smem + 12288;                      // [64][136] u16 at byte 24576
  const int wm = wave >> 1, wn = wave & 1;

  for (int pass = 0; pass < 2; ++pass) {
    const int m0 = 256 + pass * 256 + hg * 64;  // K rows then V rows
    const u16* pA[2]; const u16* pB[4];
#pragma unroll
    for (int j = 0; j < 2; ++j)
      pA[j] = A + (size_t)(m0 + j * 32 + wave * 8 + lrow) * CCH + kcl;
#pragma unroll
    for (int j = 0; j < 4; ++j)
      pB[j] = Bb + (size_t)(n0 + j * 32 + wave * 8 + lrow) * CCH + kcl;

    f32x4 acc[2][4];
#pragma unroll
    for (int i = 0; i < 2; ++i)
#pragma unroll
      for (int j = 0; j < 4; ++j) acc[i][j] = (f32x4){0.f, 0.f, 0.f, 0.f};

    for (int it = 0; it < 4; ++it) {            // K = 256, BK = 64
#pragma unroll
      for (int j = 0; j < 2; ++j) {
        __builtin_amdgcn_global_load_lds(GLB(pA[j]), LDSP(lA + (j * 256 + wave * 64) * 8), 16, 0, 0);
        pA[j] += 64;
      }
#pragma unroll
      for (int j = 0; j < 4; ++j) {
        __builtin_amdgcn_global_load_lds(GLB(pB[j]), LDSP(lB + (j * 256 + wave * 64) * 8), 16, 0, 0);
        pB[j] += 64;
      }
      __syncthreads();
#pragma unroll
      for (int w = 0; w < 2; ++w) {
        const int kcf = w * 4 + (lane >> 4);
        short8 af[2], bfr[4];
#pragma unroll
        for (int mt = 0; mt < 2; ++mt) {
          const int row = wm * 32 + mt * 16 + (lane & 15);
          af[mt] = *(const short8*)&lA[(row * 8 + (kcf ^ (row & 7))) * 8];
        }
#pragma unroll
        for (int nt = 0; nt < 4; ++nt) {
          const int row = wn * 64 + nt * 16 + (lane & 15);
          bfr[nt] = *(const short8*)&lB[(row * 8 + (kcf ^ (row & 7))) * 8];
        }
#pragma unroll
        for (int mt = 0; mt < 2; ++mt)
#pragma unroll
          for (int nt = 0; nt < 4; ++nt)
            acc[mt][nt] = __builtin_amdgcn_mfma_f32_16x16x32_bf16(af[mt], bfr[nt], acc[mt][nt], 0, 0, 0);
      }
      __syncthreads();
    }

    // epilogue -> LDS tile [64][136], row = head-local d-row, col = n-local
    u16* cl = pass ? clV : clK;
#pragma unroll
    for (int mt = 0; mt < 2; ++mt)
#pragma unroll
      for (int nt = 0; nt < 4; ++nt)
#pragma unroll
        for (int r = 0; r < 4; ++r) {
          const int row = wm * 32 + mt * 16 + (lane >> 4) * 4 + r;
          const int col = wn * 64 + nt * 16 + (lane & 15);
          const float v = acc[mt][nt][r];
          cl[row * 136 + col] = f2bf(pass ? v : __expf(v));
        }
  }
  __syncthreads();                              // clK + clV visible to all waves

  // att phase: wave = (head hh, n-half)
  const int hh = wave >> 1, nhalf = wave & 1;
  const int bh = b * 8 + hg * 2 + hh;
  f32x4 a2[2][2], al[2];
#pragma unroll
  for (int i = 0; i < 2; ++i) {
    al[i] = (f32x4){0.f, 0.f, 0.f, 0.f};
#pragma unroll
    for (int j = 0; j < 2; ++j) a2[i][j] = (f32x4){0.f, 0.f, 0.f, 0.f};
  }
  short8 ones;
#pragma unroll
  for (int j = 0; j < 8; ++j) ones[j] = (short)0x3F80;   // bf16 1.0

  const int rr = lane & 15, cc8 = (lane >> 4) * 8;
#pragma unroll
  for (int c = 0; c < 2; ++c) {                 // 2 chunks of 32 n per wave
    const int n = (nhalf * 2 + c) * 32 + cc8;
    short8 ek0 = *(const short8*)&clK[(hh * 32 + rr) * 136 + n];
    short8 ek1 = *(const short8*)&clK[(hh * 32 + 16 + rr) * 136 + n];
    short8 v0  = *(const short8*)&clV[(hh * 32 + rr) * 136 + n];
    short8 v1  = *(const short8*)&clV[(hh * 32 + 16 + rr) * 136 + n];
    a2[0][0] = __builtin_amdgcn_mfma_f32_16x16x32_bf16(ek0, v0, a2[0][0], 0, 0, 0);
    a2[0][1] = __builtin_amdgcn_mfma_f32_16x16x32_bf16(ek0, v1, a2[0][1], 0, 0, 0);
    a2[1][0] = __builtin_amdgcn_mfma_f32_16x16x32_bf16(ek1, v0, a2[1][0], 0, 0, 0);
    a2[1][1] = __builtin_amdgcn_mfma_f32_16x16x32_bf16(ek1, v1, a2[1][1], 0, 0, 0);
    al[0]    = __builtin_amdgcn_mfma_f32_16x16x32_bf16(ek0, ones, al[0], 0, 0, 0);
    al[1]    = __builtin_amdgcn_mfma_f32_16x16x32_bf16(ek1, ones, al[1], 0, 0, 0);
  }
  __syncthreads();                              // done reading clK/clV

  // pair-reduce the two n-half waves of each head in LDS, then atomicAdd
  float* red  = (float*)smem;                   // [2][32][34] f32
  float* redl = red + 2176;                     // [2][32]
  const int dq = (lane >> 4) * 4;
  if (nhalf == 1) {
#pragma unroll
    for (int dh = 0; dh < 2; ++dh) {
#pragma unroll
      for (int eh = 0; eh < 2; ++eh)
#pragma unroll
        for (int j = 0; j < 4; ++j)
          red[hh * 1088 + (dh * 16 + dq + j) * 34 + eh * 16 + rr] = a2[dh][eh][j];
      if (rr == 0)
#pragma unroll
        for (int j = 0; j < 4; ++j) redl[hh * 32 + dh * 16 + dq + j] = al[dh][j];
    }
  }
  __syncthreads();
  if (nhalf == 0) {
    float* ap = att4 + (size_t)bh * 1056;
#pragma unroll
    for (int dh = 0; dh < 2; ++dh) {
#pragma unroll
      for (int eh = 0; eh < 2; ++eh)
#pragma unroll
        for (int j = 0; j < 4; ++j) {
          const int d = dh * 16 + dq + j, e = eh * 16 + rr;
          atomicAdd(&ap[d * 32 + e], a2[dh][eh][j] + red[hh * 1088 + d * 34 + e]);
        }
      if (rr == 0)
#pragma unroll
        for (int j = 0; j < 4; ++j) {
          const int d = dh * 16 + dq + j;
          atomicAdd(&ap[1024 + d], al[dh][j] + redl[hh * 32 + d]);
        }
    }
  }
}

// ------------------------------------------------ W2_b = wp @ blockdiag(att/l)
// W2[b][o][h*32+d] = sum_e wp[o][h*32+e] * att[bh][d][e]/l[bh][d].
__global__ __launch_bounds__(256) void w2_kernel(const u16* __restrict__ wp_bf,
                                                 const float* __restrict__ att4,
                                                 u16* __restrict__ W2) {
  const int b = blockIdx.x >> 4;
  const int o0 = (blockIdx.x & 15) * 16;
  const int tid = threadIdx.x;
  const int h = tid >> 5, d = tid & 31;
  const float* ap = att4 + ((size_t)b * 8 + h) * 1056;
  const float linv = 1.f / ap[1024 + d];
  float as[32];
#pragma unroll
  for (int e = 0; e < 32; ++e) as[e] = ap[d * 32 + e] * linv;
  u16* w2p = W2 + (size_t)b * 65536;
  for (int oi = 0; oi < 16; ++oi) {
    const int o = o0 + oi;
    const uint4* wr = (const uint4*)(wp_bf + o * 256 + h * 32);
    float acc = 0.f;
#pragma unroll
    for (int j = 0; j < 4; ++j) {
      uint4 u = wr[j];
      const u16* w8 = (const u16*)&u;
#pragma unroll
      for (int t = 0; t < 8; ++t) acc += bf2f(w8[t]) * as[j * 8 + t];
    }
    w2p[o * 256 + tid] = f2bf(acc);             // coalesced u16 row writes
  }
}

// ------------------------------------------------ launch
extern "C" void kernel_launch(void* const* d_in, const int* in_sizes, int n_in,
                              void* d_out, int out_size, void* d_ws, size_t ws_size,
                              hipStream_t stream) {
  const float* x      = (const float*)d_in[0];
  const float* gn_w   = (const float*)d_in[1];
  const float* gn_b   = (const float*)d_in[2];
  const float* w_qkv  = (const float*)d_in[3];
  const float* w_proj = (const float*)d_in[4];
  const float* b_proj = (const float*)d_in[5];
  float* out = (float*)d_out;

  char* ws = (char*)d_ws;
  u16*    xnT   = (u16*)ws;                                 // 32 MiB [b][n][c], live到 final gemm
  u16*    wbf   = (u16*)(ws + 33554432ull);                 // 512 KiB (wq 768x256 + wp 256x256)
  u16*    wqT   = (u16*)(ws + 34078720ull);                 // 128 KiB (Wq_q transposed [c][d])
  u16*    W2    = (u16*)(ws + 34209792ull);                 // 2 MiB [b][256][256]
  u16*    W3    = (u16*)(ws + 36306944ull);                 // 2 MiB [b][256][256]
  float*  att4  = (float*)(ws + 38404096ull);               // 128*1056*4 = 540672 B
  float2* stats = (float2*)(ws + 38944768ull);              // 4 KiB
  u16* wq_bf = wbf;
  u16* wp_bf = wbf + 196608;

  convw_kernel<<<256, 256, 0, stream>>>(w_qkv, w_proj, wbf);
  wqt_kernel<<<dim3(4, 4), 256, 0, stream>>>(wq_bf, wqT);
  gn_stats<<<512, 256, 0, stream>>>(x, stats, att4);
  gn_apply_t<<<dim3(64, 4, 16), 256, 0, stream>>>(x, gn_w, gn_b, stats, xnT);
  gemm_kv_att<<<dim3(32, 4, 16), 256, 0, stream>>>(wq_bf, xnT, att4);
  w2_kernel<<<256, 256, 0, stream>>>(wp_bf, att4, W2);
  // W3_b = W2_b @ Wq_q  (A=W2 [o][d], Bt=wqT [c][d], C=W3 [o][c], ldc=256)
  gemm_mfma<0><<<dim3(2, 2, 16), 256, 0, stream>>>(W2, wqT, nullptr, W3,
                                                   CCH, 65536, 0L, CCH);
  // out = W3_b @ xn + b_proj  (Bt = xnT, ldc = NSP)
  gemm_mfma<1><<<dim3(32, 2, 16), 256, 0, stream>>>(W3, xnT, b_proj, out,
                                                    CCH, 65536, (long)NSP * CCH, NSP);
}

// Round 5
// 208.116 us; speedup vs baseline: 1.1865x; 1.0741x over previous
//
#include <hip/hip_runtime.h>
#include <stdint.h>

// x (16,256,64,64) fp32; 32 groups; 8 heads; head dim 32. All I/O fp32.
// Intermediates bf16 in d_ws. GEMMs: bf16 MFMA 16x16x32, BK=64, swizzled
// coalesced global_load_lds staging, LDS-staged coalesced epilogue.
// Softmax folded into att: att = diag(1/l) * sum_n exp(k) v  (no max-sub; |k|<~6).
// R7: att-output folds into w_proj: W2_b = wp @ blockdiag(att/l).
// R9: Q never materialized: out = (W2_b @ Wq_q) @ xn  (W3 = W2@Wq_q per batch).
// R10:(a) kv_att single-pass 128x128 (64 K-rows + 64 V-rows of one head pair,
//         shared B staging): half the barriers/B-loads of R9's 2-pass version,
//         smem 34816 B -> 4 blocks/CU. Epilogue split by wm (wave-uniform):
//         wm=0 -> exp->clK, wm=1 -> clV.
//     (b) launch count 8 -> 6 (~12us gap each, measured ~100us total): convw
//         and wqt merged into the gn_stats launch as independent extra blocks
//         (wqt reads fp32 source directly).
#define BATCH 16
#define CCH   256
#define NSP   4096

typedef unsigned short u16;
typedef short  short8 __attribute__((ext_vector_type(8)));   // 8 bf16 (4 VGPRs)
typedef float  f32x4  __attribute__((ext_vector_type(4)));

__device__ __forceinline__ float bf2f(u16 h) {
  union { unsigned int u; float f; } x; x.u = ((unsigned int)h) << 16; return x.f;
}
__device__ __forceinline__ u16 f2bf(float f) {
  union { float f; unsigned int u; } x; x.f = f;
  unsigned int r = 0x7fffu + ((x.u >> 16) & 1u);
  return (u16)((x.u + r) >> 16);
}

#define GLB(p) ((__attribute__((address_space(1))) void*)(p))
#define LDSP(p) ((__attribute__((address_space(3))) void*)(p))

// ------------------------------------------------ prep: GN stats + att4 zero
// + weights fp32->bf16 + wqT transpose, one launch (independent block ranges).
// blk <512: gn_stats(b=blk>>5,g=blk&31); 512..767: convw; 768..783: wqT.
__global__ __launch_bounds__(256) void prep_kernel(const float* __restrict__ x,
                                                   const float* __restrict__ wq,
                                                   const float* __restrict__ wp,
                                                   float2* __restrict__ stats,
                                                   float* __restrict__ att4,
                                                   u16* __restrict__ wbf,
                                                   u16* __restrict__ wqT) {
  __shared__ float red[8];
  __shared__ u16 ls[64][72];
  const int blk = blockIdx.x, tid = threadIdx.x;
  if (blk < 512) {
    // zero att accumulator: 128 heads * 1056 floats = 512 blocks * 264
    {
      float* az = att4 + (size_t)blk * 264;
      for (int i = tid; i < 264; i += 256) az[i] = 0.f;
    }
    const float4* xv = (const float4*)(x + (size_t)blk * 32768);
    float s = 0.f, ss = 0.f;
    for (int i = tid; i < 8192; i += 256) {
      float4 u = xv[i];
      s  += u.x + u.y + u.z + u.w;
      ss += u.x * u.x + u.y * u.y + u.z * u.z + u.w * u.w;
    }
#pragma unroll
    for (int off = 32; off > 0; off >>= 1) {
      s  += __shfl_down(s, off);
      ss += __shfl_down(ss, off);
    }
    const int wave = tid >> 6, lane = tid & 63;
    if (lane == 0) { red[wave * 2] = s; red[wave * 2 + 1] = ss; }
    __syncthreads();
    if (tid == 0) {
      const float S  = red[0] + red[2] + red[4] + red[6];
      const float SS = red[1] + red[3] + red[5] + red[7];
      const float mean = S * (1.f / 32768.f);
      const float var  = SS * (1.f / 32768.f) - mean * mean;
      stats[blk] = make_float2(mean, rsqrtf(var + 1e-5f));
    }
  } else if (blk < 768) {
    const int i = ((blk - 512) * 256 + tid) * 4;
    float4 v = (i < 196608) ? *(const float4*)(wq + i)
                            : *(const float4*)(wp + (i - 196608));
    ushort4 o;
    o.x = f2bf(v.x); o.y = f2bf(v.y); o.z = f2bf(v.z); o.w = f2bf(v.w);
    *(ushort4*)(wbf + i) = o;
  } else {
    // wqT[c][d] = bf16(wq[d][c]) for Q rows d<256; 16 blocks of 64x64 tiles
    const int t2 = blk - 768;
    const int c0 = (t2 & 3) * 64, r0 = (t2 >> 2) * 64;
#pragma unroll
    for (int j = 0; j < 4; ++j) {
      const int row = j * 16 + (tid >> 4), col = (tid & 15) * 4;
      float4 u = *(const float4*)(wq + (r0 + row) * 256 + c0 + col);
      ls[row][col]     = f2bf(u.x);
      ls[row][col + 1] = f2bf(u.y);
      ls[row][col + 2] = f2bf(u.z);
      ls[row][col + 3] = f2bf(u.w);
    }
    __syncthreads();
#pragma unroll
    for (int j = 0; j < 2; ++j) {
      const int crow = j * 32 + (tid >> 3), d8 = (tid & 7) * 8;
      u16 tmp[8];
#pragma unroll
      for (int k = 0; k < 8; ++k) tmp[k] = ls[d8 + k][crow];
      *(uint4*)(wqT + (c0 + crow) * 256 + r0 + d8) = *(uint4*)tmp;
    }
  }
}

// ------------------------------------------------ GN apply + transpose
__global__ __launch_bounds__(256) void gn_apply_t(const float* __restrict__ x,
                                                  const float* __restrict__ gw,
                                                  const float* __restrict__ gb,
                                                  const float2* __restrict__ stats,
                                                  u16* __restrict__ xnT) {
  __shared__ u16 ls[64][72];                    // [c][n], pad 72
  const int b = blockIdx.z, c0 = blockIdx.y * 64, n0 = blockIdx.x * 64;
  const int tid = threadIdx.x;
#pragma unroll
  for (int r = 0; r < 4; ++r) {
    const int cc = (tid >> 4) + r * 16;
    const int nn = (tid & 15) * 4;
    const int c = c0 + cc;
    const float2 st = stats[b * 32 + (c >> 3)];
    const float wv = gw[c] * st.y;
    const float bv = gb[c] - st.x * wv;
    float4 u = *(const float4*)(x + ((size_t)b * CCH + c) * NSP + n0 + nn);
    ushort4 o;
    o.x = f2bf(u.x * wv + bv);
    o.y = f2bf(u.y * wv + bv);
    o.z = f2bf(u.z * wv + bv);
    o.w = f2bf(u.w * wv + bv);
    *(ushort4*)&ls[cc][nn] = o;
  }
  __syncthreads();
#pragma unroll
  for (int p = 0; p < 2; ++p) {
    const int idx = tid + p * 256;              // 0..511
    const int nn = idx >> 3;
    const int cb = (idx & 7) * 8;
    u16 tmp[8];
#pragma unroll
    for (int j = 0; j < 8; ++j) tmp[j] = ls[cb + j][nn];
    *(uint4*)(xnT + ((size_t)b * NSP + n0 + nn) * CCH + c0 + cb) = *(uint4*)tmp;
  }
}

// ------------------------------------------------ MFMA GEMM, BK=64, coalesced staging
// C[b][m][n] = sum_c A[m][c]*Bt[b][n][c]; A bf16 MxK(K=256), Bt bf16 NxK.
// OUTF32: fp32 output + bias. ldc = output row stride.
template <int OUTF32>
__global__ __launch_bounds__(256) void gemm_mfma(const u16* __restrict__ A,
                                                 const u16* __restrict__ Bt,
                                                 const float* __restrict__ bias,
                                                 void* __restrict__ Cm, int M,
                                                 int aBatch, long btStride, int ldc) {
  __shared__ __align__(16) u16 smem[17408];     // 34816 B: staging 32KB / C-tile epi
  const int tid = threadIdx.x, wave = tid >> 6, lane = tid & 63;
  const int n0 = blockIdx.x * 128, m0 = blockIdx.y * 128, bz = blockIdx.z;
  const u16* Ab = A + (size_t)bz * aBatch;
  const u16* Bb = Bt + (size_t)bz * btStride;

  const int lrow = lane >> 3;                   // 0..7: row within 8-row group
  const int kcl  = ((lane & 7) ^ lrow) * 8;     // swizzled k element offset
  const u16* pA[4]; const u16* pB[4];
#pragma unroll
  for (int j = 0; j < 4; ++j) {
    const int row = j * 32 + wave * 8 + lrow;
    pA[j] = Ab + (size_t)(m0 + row) * CCH + kcl;
    pB[j] = Bb + (size_t)(n0 + row) * CCH + kcl;
  }
  u16* lA = smem;                               // 1024 granules (16KB)
  u16* lB = smem + 8192;                        // 1024 granules (16KB)

  const int wm = wave >> 1, wn = wave & 1;
  f32x4 acc[4][4];
#pragma unroll
  for (int i = 0; i < 4; ++i)
#pragma unroll
    for (int j = 0; j < 4; ++j) acc[i][j] = (f32x4){0.f, 0.f, 0.f, 0.f};

  for (int it = 0; it < 4; ++it) {              // K = 256, BK = 64
#pragma unroll
    for (int j = 0; j < 4; ++j) {
      __builtin_amdgcn_global_load_lds(GLB(pA[j]), LDSP(lA + (j * 256 + wave * 64) * 8), 16, 0, 0);
      __builtin_amdgcn_global_load_lds(GLB(pB[j]), LDSP(lB + (j * 256 + wave * 64) * 8), 16, 0, 0);
      pA[j] += 64; pB[j] += 64;
    }
    __syncthreads();
#pragma unroll
    for (int w = 0; w < 2; ++w) {               // two 32-k windows
      const int kcf = w * 4 + (lane >> 4);
      short8 af[4], bfr[4];
#pragma unroll
      for (int mt = 0; mt < 4; ++mt) {
        const int row = wm * 64 + mt * 16 + (lane & 15);
        af[mt] = *(const short8*)&lA[(row * 8 + (kcf ^ (row & 7))) * 8];
      }
#pragma unroll
      for (int nt = 0; nt < 4; ++nt) {
        const int row = wn * 64 + nt * 16 + (lane & 15);
        bfr[nt] = *(const short8*)&lB[(row * 8 + (kcf ^ (row & 7))) * 8];
      }
#pragma unroll
      for (int mt = 0; mt < 4; ++mt)
#pragma unroll
        for (int nt = 0; nt < 4; ++nt)
          acc[mt][nt] = __builtin_amdgcn_mfma_f32_16x16x32_bf16(af[mt], bfr[nt], acc[mt][nt], 0, 0, 0);
    }
    __syncthreads();
  }

  // epilogue: C/D frag col=lane&15, row=(lane>>4)*4+reg
  if (!OUTF32) {
    u16* cl = smem;                             // [128][136] u16 (34816 B)
#pragma unroll
    for (int mt = 0; mt < 4; ++mt)
#pragma unroll
      for (int nt = 0; nt < 4; ++nt)
#pragma unroll
        for (int r = 0; r < 4; ++r) {
          const int row = wm * 64 + mt * 16 + (lane >> 4) * 4 + r;
          const int col = wn * 64 + nt * 16 + (lane & 15);
          cl[row * 136 + col] = f2bf(acc[mt][nt][r]);
        }
    __syncthreads();
    u16* C = (u16*)Cm + (size_t)bz * (size_t)M * ldc;
#pragma unroll
    for (int j = 0; j < 8; ++j) {
      const int idx = tid + j * 256;            // 0..2047
      const int row = idx >> 4, chunk = idx & 15;
      *(uint4*)(C + (size_t)(m0 + row) * ldc + n0 + chunk * 8) =
          *(const uint4*)&cl[row * 136 + chunk * 8];
    }
  } else {
    float* clf = (float*)smem;                  // [64][132] fp32 per pass (33792 B)
    float* C = (float*)Cm + (size_t)bz * (size_t)M * ldc;
#pragma unroll
    for (int pass = 0; pass < 2; ++pass) {
      if (wm == pass) {
#pragma unroll
        for (int mt = 0; mt < 4; ++mt)
#pragma unroll
          for (int nt = 0; nt < 4; ++nt)
#pragma unroll
            for (int r = 0; r < 4; ++r) {
              const int rl = mt * 16 + (lane >> 4) * 4 + r;   // 0..63
              const int col = wn * 64 + nt * 16 + (lane & 15);
              clf[rl * 132 + col] = acc[mt][nt][r] + bias[m0 + pass * 64 + rl];
            }
      }
      __syncthreads();
#pragma unroll
      for (int j = 0; j < 8; ++j) {
        const int idx = tid + j * 256;          // 0..2047
        const int row = idx >> 5, chunk = idx & 31;
        *(float4*)(C + (size_t)(m0 + pass * 64 + row) * ldc + n0 + chunk * 4) =
            *(const float4*)&clf[row * 132 + chunk * 4];
      }
      __syncthreads();
    }
  }
}

// ------------------------------------------------ fused K/V GEMM + att reduction
// Single-pass 128x128: A rows = 64 K-rows + 64 V-rows of head pair hg, shared
// B staging (xnT tile loaded ONCE). Identical inner loop to gemm_mfma.
// Epilogue (wave-uniform by wm): wm=0 -> exp->clK, wm=1 -> clV, both [64][136]
// in the same 34816 B smem as staging (safe after final barrier).
// att phase: wave (hh=wave>>1, nhalf=wave&1): 12 MFMAs on head hh's LDS rows;
// n-half pairs reduced in LDS, then atomicAdd into att4.
__global__ __launch_bounds__(256, 4) void gemm_kv_att(const u16* __restrict__ A,
                                                      const u16* __restrict__ Bt,
                                                      float* __restrict__ att4) {
  __shared__ __align__(16) u16 smem[17408];     // 34816 B
  const int tid = threadIdx.x, wave = tid >> 6, lane = tid & 63;
  const int n0 = blockIdx.x * 128, hg = blockIdx.y, b = blockIdx.z;
  const u16* Bb = Bt + (size_t)b * (size_t)NSP * CCH;

  const int lrow = lane >> 3;                   // 0..7
  const int kcl  = ((lane & 7) ^ lrow) * 8;     // swizzled k element offset
  const u16* pA[4]; const u16* pB[4];
#pragma unroll
  for (int j = 0; j < 4; ++j) {
    // local row j*32+wave*8+lrow: [0,64)=K rows, [64,128)=V rows of head pair hg
    const int arow = 256 + (j >> 1) * 256 + hg * 64 + (j & 1) * 32 + wave * 8 + lrow;
    pA[j] = A  + (size_t)arow * CCH + kcl;
    pB[j] = Bb + (size_t)(n0 + j * 32 + wave * 8 + lrow) * CCH + kcl;
  }
  u16* lA = smem;                               // 16 KB
  u16* lB = smem + 8192;                        // 16 KB

  const int wm = wave >> 1, wn = wave & 1;
  f32x4 acc[4][4];
#pragma unroll
  for (int i = 0; i < 4; ++i)
#pragma unroll
    for (int j = 0; j < 4; ++j) acc[i][j] = (f32x4){0.f, 0.f, 0.f, 0.f};

  for (int it = 0; it < 4; ++it) {              // K = 256, BK = 64
#pragma unroll
    for (int j = 0; j < 4; ++j) {
      __builtin_amdgcn_global_load_lds(GLB(pA[j]), LDSP(lA + (j * 256 + wave * 64) * 8), 16, 0, 0);
      __builtin_amdgcn_global_load_lds(GLB(pB[j]), LDSP(lB + (j * 256 + wave * 64) * 8), 16, 0, 0);
      pA[j] += 64; pB[j] += 64;
    }
    __syncthreads();
#pragma unroll
    for (int w = 0; w < 2; ++w) {
      const int kcf = w * 4 + (lane >> 4);
      short8 af[4], bfr[4];
#pragma unroll
      for (int mt = 0; mt < 4; ++mt) {
        const int row = wm * 64 + mt * 16 + (lane & 15);
        af[mt] = *(const short8*)&lA[(row * 8 + (kcf ^ (row & 7))) * 8];
      }
#pragma unroll
      for (int nt = 0; nt < 4; ++nt) {
        const int row = wn * 64 + nt * 16 + (lane & 15);
        bfr[nt] = *(const short8*)&lB[(row * 8 + (kcf ^ (row & 7))) * 8];
      }
#pragma unroll
      for (int mt = 0; mt < 4; ++mt)
#pragma unroll
        for (int nt = 0; nt < 4; ++nt)
          acc[mt][nt] = __builtin_amdgcn_mfma_f32_16x16x32_bf16(af[mt], bfr[nt], acc[mt][nt], 0, 0, 0);
    }
    __syncthreads();
  }

  // epilogue -> clK (exp'ed K rows) / clV, [64][136] each
  u16* clK = smem;                              // bytes [0, 17408)
  u16* clV = smem + 8704;                       // bytes [17408, 34816)
  {
    const int rbase = (lane >> 4) * 4;
    if (wm == 0) {                              // rows 0..63 = K
#pragma unroll
      for (int mt = 0; mt < 4; ++mt)
#pragma unroll
        for (int nt = 0; nt < 4; ++nt)
#pragma unroll
          for (int r = 0; r < 4; ++r) {
            const int row = mt * 16 + rbase + r;
            const int col = wn * 64 + nt * 16 + (lane & 15);
            clK[row * 136 + col] = f2bf(__expf(acc[mt][nt][r]));
          }
    } else {                                    // rows 64..127 = V
#pragma unroll
      for (int mt = 0; mt < 4; ++mt)
#pragma unroll
        for (int nt = 0; nt < 4; ++nt)
#pragma unroll
          for (int r = 0; r < 4; ++r) {
            const int row = mt * 16 + rbase + r;
            const int col = wn * 64 + nt * 16 + (lane & 15);
            clV[row * 136 + col] = f2bf(acc[mt][nt][r]);
          }
    }
  }
  __syncthreads();                              // clK + clV visible to all waves

  // att phase: wave = (head hh in pair, n-half)
  const int hh = wave >> 1, nhalf = wave & 1;
  const int bh = b * 8 + hg * 2 + hh;
  f32x4 a2[2][2], al[2];
#pragma unroll
  for (int i = 0; i < 2; ++i) {
    al[i] = (f32x4){0.f, 0.f, 0.f, 0.f};
#pragma unroll
    for (int j = 0; j < 2; ++j) a2[i][j] = (f32x4){0.f, 0.f, 0.f, 0.f};
  }
  short8 ones;
#pragma unroll
  for (int j = 0; j < 8; ++j) ones[j] = (short)0x3F80;   // bf16 1.0

  const int rr = lane & 15, cc8 = (lane >> 4) * 8;
#pragma unroll
  for (int c = 0; c < 2; ++c) {                 // 2 chunks of 32 n per wave
    const int n = (nhalf * 2 + c) * 32 + cc8;
    short8 ek0 = *(const short8*)&clK[(hh * 32 + rr) * 136 + n];
    short8 ek1 = *(const short8*)&clK[(hh * 32 + 16 + rr) * 136 + n];
    short8 v0  = *(const short8*)&clV[(hh * 32 + rr) * 136 + n];
    short8 v1  = *(const short8*)&clV[(hh * 32 + 16 + rr) * 136 + n];
    a2[0][0] = __builtin_amdgcn_mfma_f32_16x16x32_bf16(ek0, v0, a2[0][0], 0, 0, 0);
    a2[0][1] = __builtin_amdgcn_mfma_f32_16x16x32_bf16(ek0, v1, a2[0][1], 0, 0, 0);
    a2[1][0] = __builtin_amdgcn_mfma_f32_16x16x32_bf16(ek1, v0, a2[1][0], 0, 0, 0);
    a2[1][1] = __builtin_amdgcn_mfma_f32_16x16x32_bf16(ek1, v1, a2[1][1], 0, 0, 0);
    al[0]    = __builtin_amdgcn_mfma_f32_16x16x32_bf16(ek0, ones, al[0], 0, 0, 0);
    al[1]    = __builtin_amdgcn_mfma_f32_16x16x32_bf16(ek1, ones, al[1], 0, 0, 0);
  }
  __syncthreads();                              // done reading clK/clV

  // pair-reduce the two n-half waves of each head in LDS, then atomicAdd
  float* red  = (float*)smem;                   // [2][32][34] f32 (8704 B)
  float* redl = red + 2176;                     // [2][32]
  const int dq = (lane >> 4) * 4;
  if (nhalf == 1) {
#pragma unroll
    for (int dh = 0; dh < 2; ++dh) {
#pragma unroll
      for (int eh = 0; eh < 2; ++eh)
#pragma unroll
        for (int j = 0; j < 4; ++j)
          red[hh * 1088 + (dh * 16 + dq + j) * 34 + eh * 16 + rr] = a2[dh][eh][j];
      if (rr == 0)
#pragma unroll
        for (int j = 0; j < 4; ++j) redl[hh * 32 + dh * 16 + dq + j] = al[dh][j];
    }
  }
  __syncthreads();
  if (nhalf == 0) {
    float* ap = att4 + (size_t)bh * 1056;
#pragma unroll
    for (int dh = 0; dh < 2; ++dh) {
#pragma unroll
      for (int eh = 0; eh < 2; ++eh)
#pragma unroll
        for (int j = 0; j < 4; ++j) {
          const int d = dh * 16 + dq + j, e = eh * 16 + rr;
          atomicAdd(&ap[d * 32 + e], a2[dh][eh][j] + red[hh * 1088 + d * 34 + e]);
        }
      if (rr == 0)
#pragma unroll
        for (int j = 0; j < 4; ++j) {
          const int d = dh * 16 + dq + j;
          atomicAdd(&ap[1024 + d], al[dh][j] + redl[hh * 32 + d]);
        }
    }
  }
}

// ------------------------------------------------ W2_b = wp @ blockdiag(att/l)
// W2[b][o][h*32+d] = sum_e wp[o][h*32+e] * att[bh][d][e]/l[bh][d].
__global__ __launch_bounds__(256) void w2_kernel(const u16* __restrict__ wp_bf,
                                                 const float* __restrict__ att4,
                                                 u16* __restrict__ W2) {
  const int b = blockIdx.x >> 4;
  const int o0 = (blockIdx.x & 15) * 16;
  const int tid = threadIdx.x;
  const int h = tid >> 5, d = tid & 31;
  const float* ap = att4 + ((size_t)b * 8 + h) * 1056;
  const float linv = 1.f / ap[1024 + d];
  float as[32];
#pragma unroll
  for (int e = 0; e < 32; ++e) as[e] = ap[d * 32 + e] * linv;
  u16* w2p = W2 + (size_t)b * 65536;
  for (int oi = 0; oi < 16; ++oi) {
    const int o = o0 + oi;
    const uint4* wr = (const uint4*)(wp_bf + o * 256 + h * 32);
    float acc = 0.f;
#pragma unroll
    for (int j = 0; j < 4; ++j) {
      uint4 u = wr[j];
      const u16* w8 = (const u16*)&u;
#pragma unroll
      for (int t = 0; t < 8; ++t) acc += bf2f(w8[t]) * as[j * 8 + t];
    }
    w2p[o * 256 + tid] = f2bf(acc);             // coalesced u16 row writes
  }
}

// ------------------------------------------------ launch
extern "C" void kernel_launch(void* const* d_in, const int* in_sizes, int n_in,
                              void* d_out, int out_size, void* d_ws, size_t ws_size,
                              hipStream_t stream) {
  const float* x      = (const float*)d_in[0];
  const float* gn_w   = (const float*)d_in[1];
  const float* gn_b   = (const float*)d_in[2];
  const float* w_qkv  = (const float*)d_in[3];
  const float* w_proj = (const float*)d_in[4];
  const float* b_proj = (const float*)d_in[5];
  float* out = (float*)d_out;

  char* ws = (char*)d_ws;
  u16*    xnT   = (u16*)ws;                                 // 32 MiB [b][n][c], live through final gemm
  u16*    wbf   = (u16*)(ws + 33554432ull);                 // 512 KiB (wq 768x256 + wp 256x256)
  u16*    wqT   = (u16*)(ws + 34078720ull);                 // 128 KiB (Wq_q transposed [c][d])
  u16*    W2    = (u16*)(ws + 34209792ull);                 // 2 MiB [b][256][256]
  u16*    W3    = (u16*)(ws + 36306944ull);                 // 2 MiB [b][256][256]
  float*  att4  = (float*)(ws + 38404096ull);               // 128*1056*4 = 540672 B
  float2* stats = (float2*)(ws + 38944768ull);              // 4 KiB
  u16* wq_bf = wbf;
  u16* wp_bf = wbf + 196608;

  prep_kernel<<<784, 256, 0, stream>>>(x, w_qkv, w_proj, stats, att4, wbf, wqT);
  gn_apply_t<<<dim3(64, 4, 16), 256, 0, stream>>>(x, gn_w, gn_b, stats, xnT);
  gemm_kv_att<<<dim3(32, 4, 16), 256, 0, stream>>>(wq_bf, xnT, att4);
  w2_kernel<<<256, 256, 0, stream>>>(wp_bf, att4, W2);
  // W3_b = W2_b @ Wq_q  (A=W2 [o][d], Bt=wqT [c][d], C=W3 [o][c], ldc=256)
  gemm_mfma<0><<<dim3(2, 2, 16), 256, 0, stream>>>(W2, wqT, nullptr, W3,
                                                   CCH, 65536, 0L, CCH);
  // out = W3_b @ xn + b_proj  (Bt = xnT, ldc = NSP)
  gemm_mfma<1><<<dim3(32, 2, 16), 256, 0, stream>>>(W3, xnT, b_proj, out,
                                                    CCH, 65536, (long)NSP * CCH, NSP);
}